// Round 1
// baseline (1928.362 us; speedup 1.0000x reference)
//
#include <hip/hip_runtime.h>

#define BLOCK 128   // 2 waves/block; LDS 64KB -> 2 blocks/CU (4 waves/CU)

// E[silu(Z)^2] over N(0,1) = 0.3557704 -> 1/sqrt = 1.6765444
__device__ __forceinline__ float silu_n(float x) {
    return x / (1.0f + __expf(-x)) * 1.6765444f;
}

__device__ __forceinline__ void atomAddF(float* p, float v) {
    unsafeAtomicAdd(p, v);   // hardware global_atomic_add_f32 on gfx950
}

__global__ void __launch_bounds__(BLOCK) fused_mp(
    const float* __restrict__ nf,   // (N, 256): [0:64] s, [64:256] v (64,3)
    const float* __restrict__ ea,   // (E, 11):  [0:8] radial, [8:11] ev
    const int*   __restrict__ snd,
    const int*   __restrict__ rcv,
    const float* __restrict__ w0,   // (8,64)
    const float* __restrict__ w1,   // (64,64)
    const float* __restrict__ w2,   // (64,64)
    const float* __restrict__ w3,   // (64,256)
    float* __restrict__ out,        // (N, 512), pre-zeroed
    int E)
{
    __shared__ float lds_h[BLOCK * 64];   // hidden vec, [j][tid], per-thread column
    __shared__ float lds_st[BLOCK * 64];  // per-wave mix staging (XOR swizzled)

    const int tid  = threadIdx.x;
    const int lane = tid & 63;
    const int wv   = tid >> 6;
    const int ebase = blockIdx.x * BLOCK;
    const int e = ebase + tid;
    const bool valid = e < E;

    float es[8];
    float ev0 = 0.f, ev1 = 0.f, ev2 = 0.f;
    int sidx = 0, ridx = 0;
    if (valid) {
        const float* p = ea + (size_t)e * 11;
        #pragma unroll
        for (int k = 0; k < 8; k++) es[k] = p[k];
        ev0 = p[8]; ev1 = p[9]; ev2 = p[10];
        sidx = snd[e]; ridx = rcv[e];
    } else {
        #pragma unroll
        for (int k = 0; k < 8; k++) es[k] = 0.f;
    }

    // ---- layer 0: (8 -> 64), scale 1/sqrt(8), silu*ACT_CST
    for (int j = 0; j < 64; j++) {
        float a = 0.f;
        #pragma unroll
        for (int k = 0; k < 8; k++) a += es[k] * w0[k * 64 + j];
        lds_h[j * BLOCK + tid] = silu_n(a * 0.35355339f);
    }

    float acc[64];

    // ---- layer 1: (64 -> 64), scale 1/8
    #pragma unroll
    for (int j = 0; j < 64; j++) acc[j] = 0.f;
    for (int k = 0; k < 64; k++) {
        float hk = lds_h[k * BLOCK + tid];
        const float* wr = w1 + k * 64;
        #pragma unroll
        for (int j = 0; j < 64; j++) acc[j] += hk * wr[j];
    }
    #pragma unroll
    for (int j = 0; j < 64; j++) lds_h[j * BLOCK + tid] = silu_n(acc[j] * 0.125f);

    // ---- layer 2: (64 -> 64), scale 1/8
    #pragma unroll
    for (int j = 0; j < 64; j++) acc[j] = 0.f;
    for (int k = 0; k < 64; k++) {
        float hk = lds_h[k * BLOCK + tid];
        const float* wr = w2 + k * 64;
        #pragma unroll
        for (int j = 0; j < 64; j++) acc[j] += hk * wr[j];
    }
    #pragma unroll
    for (int j = 0; j < 64; j++) lds_h[j * BLOCK + tid] = silu_n(acc[j] * 0.125f);

    // ---- layer 3 (64 -> 256) in 4 chunks of 64, fused with message scatter.
    // mix chunk folds layer scale 1/8 and the final 1/sqrt(16)=0.25.
    const int wave_base = ebase + wv * 64;
    int wn = E - wave_base;
    const int wave_nvalid = wn < 0 ? 0 : (wn > 64 ? 64 : wn);
    float* st = lds_st + wv * 64 * 64;

    auto compute_chunk = [&](int c) {
        #pragma unroll
        for (int j = 0; j < 64; j++) acc[j] = 0.f;
        for (int k = 0; k < 64; k++) {
            float hk = lds_h[k * BLOCK + tid];
            const float* wr = w3 + k * 256 + c * 64;
            #pragma unroll
            for (int j = 0; j < 64; j++) acc[j] += hk * wr[j];
        }
        // stage swizzled: writer lane L puts value j at [j*64 + (L^j)]
        #pragma unroll
        for (int j = 0; j < 64; j++) st[j * 64 + (lane ^ j)] = acc[j] * (0.125f * 0.25f);
    };

    // chunk 0: msg_s[0:64] = ms * mix -> out[:, 0:64]
    compute_chunk(0);
    for (int i = 0; i < wave_nvalid; i++) {
        int sI = __shfl(sidx, i);
        int rI = __shfl(ridx, i);
        float m = st[lane * 64 + (i ^ lane)];
        float v = nf[(size_t)sI * 256 + lane] * m;
        atomAddF(&out[(size_t)rI * 512 + lane], v);
    }

    // chunk 1: msg_s[64:128] = (mv . ev)*INV_SQRT3 * mix -> out[:, 64:128]
    compute_chunk(1);
    for (int i = 0; i < wave_nvalid; i++) {
        int sI = __shfl(sidx, i);
        int rI = __shfl(ridx, i);
        float a0 = __shfl(ev0, i), a1 = __shfl(ev1, i), a2 = __shfl(ev2, i);
        const float* vr = nf + (size_t)sI * 256 + 64 + 3 * lane;
        float d = vr[0] * a0 + vr[1] * a1 + vr[2] * a2;
        float m = st[lane * 64 + (i ^ lane)];
        atomAddF(&out[(size_t)rI * 512 + 64 + lane], d * 0.57735027f * m);
    }

    // chunk 2: msg_v rows 0:64 (= mv) * mixv -> out[:, 128 + 3*m + c], m=lane
    compute_chunk(2);
    for (int i = 0; i < wave_nvalid; i++) {
        int sI = __shfl(sidx, i);
        int rI = __shfl(ridx, i);
        const float* vr = nf + (size_t)sI * 256 + 64 + 3 * lane;
        float m = st[lane * 64 + (i ^ lane)];
        float* orow = out + (size_t)rI * 512 + 128 + 3 * lane;
        atomAddF(orow + 0, vr[0] * m);
        atomAddF(orow + 1, vr[1] * m);
        atomAddF(orow + 2, vr[2] * m);
    }

    // chunk 3: msg_v rows 64:128 (= ms x ev) * mixv -> out[:, 320 + 3*m + c], m=lane
    compute_chunk(3);
    for (int i = 0; i < wave_nvalid; i++) {
        int sI = __shfl(sidx, i);
        int rI = __shfl(ridx, i);
        float a0 = __shfl(ev0, i), a1 = __shfl(ev1, i), a2 = __shfl(ev2, i);
        float sv = nf[(size_t)sI * 256 + lane];
        float m = st[lane * 64 + (i ^ lane)];
        float* orow = out + (size_t)rI * 512 + 320 + 3 * lane;
        atomAddF(orow + 0, sv * a0 * m);
        atomAddF(orow + 1, sv * a1 * m);
        atomAddF(orow + 2, sv * a2 * m);
    }
}

extern "C" void kernel_launch(void* const* d_in, const int* in_sizes, int n_in,
                              void* d_out, int out_size, void* d_ws, size_t ws_size,
                              hipStream_t stream)
{
    const float* nf = (const float*)d_in[0];
    const float* ea = (const float*)d_in[1];
    const int*   sn = (const int*)  d_in[2];
    const int*   rc = (const int*)  d_in[3];
    const float* w0 = (const float*)d_in[4];
    const float* w1 = (const float*)d_in[5];
    const float* w2 = (const float*)d_in[6];
    const float* w3 = (const float*)d_in[7];
    float* out = (float*)d_out;
    const int E = in_sizes[2];

    hipMemsetAsync(d_out, 0, (size_t)out_size * sizeof(float), stream);
    const int blocks = (E + BLOCK - 1) / BLOCK;
    fused_mp<<<blocks, BLOCK, 0, stream>>>(nf, ea, sn, rc, w0, w1, w2, w3, out, E);
}

// Round 2
// 791.813 us; speedup vs baseline: 2.4354x; 2.4354x over previous
//
#include <hip/hip_runtime.h>

// E[silu(Z)^2] over N(0,1) = 0.3557704 -> 1/sqrt = 1.6765444
__device__ __forceinline__ float silu_n(float x) {
    return x / (1.0f + __expf(-x)) * 1.6765444f;
}

__device__ __forceinline__ unsigned short f2b(float f) {   // fp32 -> bf16 RNE
    unsigned int u = __float_as_uint(f);
    u += 0x7FFF + ((u >> 16) & 1);
    return (unsigned short)(u >> 16);
}
__device__ __forceinline__ float b2f(unsigned short u) {
    return __uint_as_float(((unsigned int)u) << 16);
}
__device__ __forceinline__ unsigned int pk2(float a, float b) {
    return (unsigned int)f2b(a) | ((unsigned int)f2b(b) << 16);
}

// ---------------- sort-by-receiver infrastructure ----------------

__global__ void hist_kernel(const int* __restrict__ rcv, int* __restrict__ cnt, int E) {
    int e = blockIdx.x * blockDim.x + threadIdx.x;
    if (e < E) atomicAdd(&cnt[rcv[e]], 1);
}

__global__ __launch_bounds__(1024) void scan_kernel(
    const int* __restrict__ cnt, int* __restrict__ offs, int* __restrict__ wptr,
    int N, int E)
{
    __shared__ int sd[1024];
    const int tid = threadIdx.x;
    const int C = (N + 1023) >> 10;
    const int b = tid * C;
    const int en = min(b + C, N);
    int sum = 0;
    for (int i = b; i < en; i++) sum += cnt[i];
    sd[tid] = sum;
    __syncthreads();
    for (int off = 1; off < 1024; off <<= 1) {
        int t = (tid >= off) ? sd[tid - off] : 0;
        __syncthreads();
        sd[tid] += t;
        __syncthreads();
    }
    int run = sd[tid] - sum;          // exclusive prefix
    for (int i = b; i < en; i++) {
        offs[i] = run; wptr[i] = run;
        run += cnt[i];
    }
    if (tid == 0) offs[N] = E;
}

__global__ void scatter_kernel(const int* __restrict__ rcv, int* __restrict__ wptr,
                               int* __restrict__ perm, int E) {
    int e = blockIdx.x * blockDim.x + threadIdx.x;
    if (e < E) {
        int p = atomicAdd(&wptr[rcv[e]], 1);
        perm[p] = e;
    }
}

// ---------------- kernel A: per-edge MLP in receiver-sorted order ----------------
// Writes mix (bf16, all layer scales + 1/sqrt(AVG_NEIGH) folded in), sorted
// sender ids and edge vectors.

#define ABLK 128

__global__ __launch_bounds__(ABLK) void mlp_sorted(
    const float* __restrict__ ea,     // (E,11)
    const int*   __restrict__ snd,
    const int*   __restrict__ perm,   // sorted pos -> edge id
    int*         __restrict__ ssort,  // (E)
    float4*      __restrict__ evq,    // (E)
    unsigned short* __restrict__ mixb,// (E,256) bf16
    const float* __restrict__ w0, const float* __restrict__ w1,
    const float* __restrict__ w2, const float* __restrict__ w3,
    int E)
{
    __shared__ float lds_h[ABLK * 64];   // per-thread private column [j][tid]

    const int tid = threadIdx.x;
    const int p = blockIdx.x * ABLK + tid;
    const bool valid = p < E;
    const int pc = valid ? p : (E - 1);
    const int e = perm[pc];

    const float* arow = ea + (size_t)e * 11;
    float es[8];
    #pragma unroll
    for (int k = 0; k < 8; k++) es[k] = arow[k];
    float ev0 = arow[8], ev1 = arow[9], ev2 = arow[10];

    if (valid) {
        ssort[p] = snd[e];
        evq[p] = make_float4(ev0, ev1, ev2, 0.f);
    }

    // layer 0: 8 -> 64, scale 1/sqrt(8)
    for (int j = 0; j < 64; j++) {
        float a = 0.f;
        #pragma unroll
        for (int k = 0; k < 8; k++) a += es[k] * w0[k * 64 + j];
        lds_h[j * ABLK + tid] = silu_n(a * 0.35355339f);
    }

    float acc[64];

    // layer 1: 64 -> 64, scale 1/8
    #pragma unroll
    for (int j = 0; j < 64; j++) acc[j] = 0.f;
    for (int k = 0; k < 64; k++) {
        float hk = lds_h[k * ABLK + tid];
        const float* wr = w1 + k * 64;
        #pragma unroll
        for (int j = 0; j < 64; j++) acc[j] += hk * wr[j];
    }
    #pragma unroll
    for (int j = 0; j < 64; j++) lds_h[j * ABLK + tid] = silu_n(acc[j] * 0.125f);

    // layer 2: 64 -> 64, scale 1/8
    #pragma unroll
    for (int j = 0; j < 64; j++) acc[j] = 0.f;
    for (int k = 0; k < 64; k++) {
        float hk = lds_h[k * ABLK + tid];
        const float* wr = w2 + k * 64;
        #pragma unroll
        for (int j = 0; j < 64; j++) acc[j] += hk * wr[j];
    }
    #pragma unroll
    for (int j = 0; j < 64; j++) lds_h[j * ABLK + tid] = silu_n(acc[j] * 0.125f);

    // layer 3: 64 -> 256 in 4 chunks; fold 1/8 * 1/sqrt(16) = 0.03125
    for (int c = 0; c < 4; c++) {
        #pragma unroll
        for (int j = 0; j < 64; j++) acc[j] = 0.f;
        for (int k = 0; k < 64; k++) {
            float hk = lds_h[k * ABLK + tid];
            const float* wr = w3 + k * 256 + c * 64;
            #pragma unroll
            for (int j = 0; j < 64; j++) acc[j] += hk * wr[j];
        }
        if (valid) {
            uint4* dst = (uint4*)(mixb + (size_t)p * 256 + c * 64);
            #pragma unroll
            for (int q = 0; q < 8; q++) {
                uint4 v;
                v.x = pk2(acc[8*q+0] * 0.03125f, acc[8*q+1] * 0.03125f);
                v.y = pk2(acc[8*q+2] * 0.03125f, acc[8*q+3] * 0.03125f);
                v.z = pk2(acc[8*q+4] * 0.03125f, acc[8*q+5] * 0.03125f);
                v.w = pk2(acc[8*q+6] * 0.03125f, acc[8*q+7] * 0.03125f);
                dst[q] = v;
            }
        }
    }
}

// ---------------- kernel B: one wave per node, CSR walk, zero atomics ----------------

__global__ __launch_bounds__(64) void gather_nodes(
    const float* __restrict__ nf,
    const int*   __restrict__ offs,
    const int*   __restrict__ ssort,
    const float4* __restrict__ evq,
    const unsigned short* __restrict__ mixb,
    float* __restrict__ out)
{
    const int n = blockIdx.x;
    const int lane = threadIdx.x;
    const int p0 = offs[n], p1 = offs[n + 1];

    float s1 = 0.f, s2 = 0.f;
    float a10 = 0.f, a11 = 0.f, a12 = 0.f;
    float a20 = 0.f, a21 = 0.f, a22 = 0.f;

    for (int p = p0; p < p1; p++) {
        const int s = ssort[p];
        const float4 ev = evq[p];
        const unsigned short* mr = mixb + (size_t)p * 256;
        float m0 = b2f(mr[lane]);
        float m1 = b2f(mr[64 + lane]);
        float m2 = b2f(mr[128 + lane]);
        float m3 = b2f(mr[192 + lane]);
        const float* nrow = nf + (size_t)s * 256;
        float sv = nrow[lane];
        const float* vr = nrow + 64 + 3 * lane;
        float v0 = vr[0], v1 = vr[1], v2 = vr[2];

        s1 += sv * m0;
        s2 += (v0 * ev.x + v1 * ev.y + v2 * ev.z) * m1;
        a10 += v0 * m2; a11 += v1 * m2; a12 += v2 * m2;
        float t = sv * m3;
        a20 += t * ev.x; a21 += t * ev.y; a22 += t * ev.z;
    }

    float* orow = out + (size_t)n * 512;
    orow[lane] = s1;
    orow[64 + lane] = s2 * 0.57735027f;   // INV_SQRT3 applied once
    float* o1 = orow + 128 + 3 * lane;
    o1[0] = a10; o1[1] = a11; o1[2] = a12;
    float* o2 = orow + 320 + 3 * lane;
    o2[0] = a20; o2[1] = a21; o2[2] = a22;
}

// ---------------- fallback (round-1 fused kernel) if ws too small ----------------

#define BLOCK 128

__device__ __forceinline__ void atomAddF(float* p, float v) { unsafeAtomicAdd(p, v); }

__global__ void __launch_bounds__(BLOCK) fused_mp(
    const float* __restrict__ nf, const float* __restrict__ ea,
    const int* __restrict__ snd, const int* __restrict__ rcv,
    const float* __restrict__ w0, const float* __restrict__ w1,
    const float* __restrict__ w2, const float* __restrict__ w3,
    float* __restrict__ out, int E)
{
    __shared__ float lds_h[BLOCK * 64];
    __shared__ float lds_st[BLOCK * 64];
    const int tid = threadIdx.x;
    const int lane = tid & 63;
    const int wv = tid >> 6;
    const int ebase = blockIdx.x * BLOCK;
    const int e = ebase + tid;
    const bool valid = e < E;

    float es[8];
    float ev0 = 0.f, ev1 = 0.f, ev2 = 0.f;
    int sidx = 0, ridx = 0;
    if (valid) {
        const float* p = ea + (size_t)e * 11;
        #pragma unroll
        for (int k = 0; k < 8; k++) es[k] = p[k];
        ev0 = p[8]; ev1 = p[9]; ev2 = p[10];
        sidx = snd[e]; ridx = rcv[e];
    } else {
        #pragma unroll
        for (int k = 0; k < 8; k++) es[k] = 0.f;
    }

    for (int j = 0; j < 64; j++) {
        float a = 0.f;
        #pragma unroll
        for (int k = 0; k < 8; k++) a += es[k] * w0[k * 64 + j];
        lds_h[j * BLOCK + tid] = silu_n(a * 0.35355339f);
    }
    float acc[64];
    #pragma unroll
    for (int j = 0; j < 64; j++) acc[j] = 0.f;
    for (int k = 0; k < 64; k++) {
        float hk = lds_h[k * BLOCK + tid];
        const float* wr = w1 + k * 64;
        #pragma unroll
        for (int j = 0; j < 64; j++) acc[j] += hk * wr[j];
    }
    #pragma unroll
    for (int j = 0; j < 64; j++) lds_h[j * BLOCK + tid] = silu_n(acc[j] * 0.125f);
    #pragma unroll
    for (int j = 0; j < 64; j++) acc[j] = 0.f;
    for (int k = 0; k < 64; k++) {
        float hk = lds_h[k * BLOCK + tid];
        const float* wr = w2 + k * 64;
        #pragma unroll
        for (int j = 0; j < 64; j++) acc[j] += hk * wr[j];
    }
    #pragma unroll
    for (int j = 0; j < 64; j++) lds_h[j * BLOCK + tid] = silu_n(acc[j] * 0.125f);

    const int wave_base = ebase + wv * 64;
    int wn = E - wave_base;
    const int wave_nvalid = wn < 0 ? 0 : (wn > 64 ? 64 : wn);
    float* st = lds_st + wv * 64 * 64;

    auto compute_chunk = [&](int c) {
        #pragma unroll
        for (int j = 0; j < 64; j++) acc[j] = 0.f;
        for (int k = 0; k < 64; k++) {
            float hk = lds_h[k * BLOCK + tid];
            const float* wr = w3 + k * 256 + c * 64;
            #pragma unroll
            for (int j = 0; j < 64; j++) acc[j] += hk * wr[j];
        }
        #pragma unroll
        for (int j = 0; j < 64; j++) st[j * 64 + (lane ^ j)] = acc[j] * (0.125f * 0.25f);
    };

    compute_chunk(0);
    for (int i = 0; i < wave_nvalid; i++) {
        int sI = __shfl(sidx, i);
        int rI = __shfl(ridx, i);
        float m = st[lane * 64 + (i ^ lane)];
        atomAddF(&out[(size_t)rI * 512 + lane], nf[(size_t)sI * 256 + lane] * m);
    }
    compute_chunk(1);
    for (int i = 0; i < wave_nvalid; i++) {
        int sI = __shfl(sidx, i);
        int rI = __shfl(ridx, i);
        float a0 = __shfl(ev0, i), a1 = __shfl(ev1, i), a2 = __shfl(ev2, i);
        const float* vr = nf + (size_t)sI * 256 + 64 + 3 * lane;
        float d = vr[0] * a0 + vr[1] * a1 + vr[2] * a2;
        float m = st[lane * 64 + (i ^ lane)];
        atomAddF(&out[(size_t)rI * 512 + 64 + lane], d * 0.57735027f * m);
    }
    compute_chunk(2);
    for (int i = 0; i < wave_nvalid; i++) {
        int sI = __shfl(sidx, i);
        int rI = __shfl(ridx, i);
        const float* vr = nf + (size_t)sI * 256 + 64 + 3 * lane;
        float m = st[lane * 64 + (i ^ lane)];
        float* orow = out + (size_t)rI * 512 + 128 + 3 * lane;
        atomAddF(orow + 0, vr[0] * m);
        atomAddF(orow + 1, vr[1] * m);
        atomAddF(orow + 2, vr[2] * m);
    }
    compute_chunk(3);
    for (int i = 0; i < wave_nvalid; i++) {
        int sI = __shfl(sidx, i);
        int rI = __shfl(ridx, i);
        float a0 = __shfl(ev0, i), a1 = __shfl(ev1, i), a2 = __shfl(ev2, i);
        float sv = nf[(size_t)sI * 256 + lane];
        float m = st[lane * 64 + (i ^ lane)];
        float* orow = out + (size_t)rI * 512 + 320 + 3 * lane;
        atomAddF(orow + 0, sv * a0 * m);
        atomAddF(orow + 1, sv * a1 * m);
        atomAddF(orow + 2, sv * a2 * m);
    }
}

// ---------------- launch ----------------

static inline size_t al256(size_t x) { return (x + 255) & ~(size_t)255; }

extern "C" void kernel_launch(void* const* d_in, const int* in_sizes, int n_in,
                              void* d_out, int out_size, void* d_ws, size_t ws_size,
                              hipStream_t stream)
{
    const float* nf = (const float*)d_in[0];
    const float* ea = (const float*)d_in[1];
    const int*   sn = (const int*)  d_in[2];
    const int*   rc = (const int*)  d_in[3];
    const float* w0 = (const float*)d_in[4];
    const float* w1 = (const float*)d_in[5];
    const float* w2 = (const float*)d_in[6];
    const float* w3 = (const float*)d_in[7];
    float* out = (float*)d_out;
    const int E = in_sizes[2];
    const int N = in_sizes[0] / 256;

    // workspace layout
    size_t o_cnt  = 0;
    size_t o_offs = o_cnt  + al256((size_t)(N + 1) * 4);
    size_t o_wptr = o_offs + al256((size_t)(N + 1) * 4);
    size_t o_perm = o_wptr + al256((size_t)N * 4);
    size_t o_ssrt = o_perm + al256((size_t)E * 4);
    size_t o_evq  = o_ssrt + al256((size_t)E * 4);
    size_t o_mix  = o_evq  + al256((size_t)E * 16);
    size_t need   = o_mix  + (size_t)E * 512;   // bf16 mix: E*256*2

    if (ws_size < need) {
        // fallback: fused atomic kernel (slow but correct)
        hipMemsetAsync(d_out, 0, (size_t)out_size * sizeof(float), stream);
        const int blocks = (E + BLOCK - 1) / BLOCK;
        fused_mp<<<blocks, BLOCK, 0, stream>>>(nf, ea, sn, rc, w0, w1, w2, w3, out, E);
        return;
    }

    char* ws = (char*)d_ws;
    int* cnt  = (int*)(ws + o_cnt);
    int* offs = (int*)(ws + o_offs);
    int* wptr = (int*)(ws + o_wptr);
    int* perm = (int*)(ws + o_perm);
    int* ssrt = (int*)(ws + o_ssrt);
    float4* evq = (float4*)(ws + o_evq);
    unsigned short* mixb = (unsigned short*)(ws + o_mix);

    hipMemsetAsync(cnt, 0, (size_t)(N + 1) * 4, stream);
    hist_kernel<<<(E + 255) / 256, 256, 0, stream>>>(rc, cnt, E);
    scan_kernel<<<1, 1024, 0, stream>>>(cnt, offs, wptr, N, E);
    scatter_kernel<<<(E + 255) / 256, 256, 0, stream>>>(rc, wptr, perm, E);
    mlp_sorted<<<(E + ABLK - 1) / ABLK, ABLK, 0, stream>>>(
        ea, sn, perm, ssrt, evq, mixb, w0, w1, w2, w3, E);
    gather_nodes<<<N, 64, 0, stream>>>(nf, offs, ssrt, evq, mixb, out);
}

// Round 3
// 329.087 us; speedup vs baseline: 5.8597x; 2.4061x over previous
//
#include <hip/hip_runtime.h>

typedef __attribute__((ext_vector_type(8))) __bf16 bf16x8;
typedef __attribute__((ext_vector_type(4))) float f32x4;

#define HP 72      // padded bf16 per hidden row (144 B, 16B-aligned, 2-way-bank only)
#define MIXP 264   // padded bf16 per mix staging row (528 B)

// E[silu(Z)^2] over N(0,1) = 0.3557704 -> 1/sqrt = 1.6765444 (ACT_CST)
__device__ __forceinline__ float silu_n(float x) {
    return x / (1.0f + __expf(-x)) * 1.6765444f;
}

__device__ __forceinline__ unsigned short f2b(float f) {
    unsigned int u = __float_as_uint(f);
    u += 0x7FFF + ((u >> 16) & 1);
    return (unsigned short)(u >> 16);
}
__device__ __forceinline__ float b2f(unsigned short u) {
    return __uint_as_float(((unsigned int)u) << 16);
}

// ---------------- sort-by-receiver infrastructure ----------------

__global__ void hist_kernel(const int* __restrict__ rcv, int* __restrict__ cnt, int E) {
    int e = blockIdx.x * blockDim.x + threadIdx.x;
    if (e < E) atomicAdd(&cnt[rcv[e]], 1);
}

__global__ __launch_bounds__(1024) void scan_kernel(
    const int* __restrict__ cnt, int* __restrict__ offs, int* __restrict__ wptr,
    int N, int E)
{
    __shared__ int sd[1024];
    const int tid = threadIdx.x;
    const int C = (N + 1023) >> 10;
    const int b = tid * C;
    const int en = min(b + C, N);
    int sum = 0;
    for (int i = b; i < en; i++) sum += cnt[i];
    sd[tid] = sum;
    __syncthreads();
    for (int off = 1; off < 1024; off <<= 1) {
        int t = (tid >= off) ? sd[tid - off] : 0;
        __syncthreads();
        sd[tid] += t;
        __syncthreads();
    }
    int run = sd[tid] - sum;
    for (int i = b; i < en; i++) {
        offs[i] = run; wptr[i] = run;
        run += cnt[i];
    }
    if (tid == 0) offs[N] = E;
}

__global__ void scatter_kernel(const int* __restrict__ rcv, int* __restrict__ wptr,
                               int* __restrict__ perm, int E) {
    int e = blockIdx.x * blockDim.x + threadIdx.x;
    if (e < E) {
        int p = atomicAdd(&wptr[rcv[e]], 1);
        perm[p] = e;
    }
}

// ---------------- weight pre-swizzle into MFMA B-fragment order ----------------
// B-frag for mfma_f32_16x16x32_bf16: lane l holds B[k][n], n=l&15, k=(l>>4)*8+j.
// Layout: [frag][lane][8] contiguous; frag = (colstrip*2 + kstep) (+64w chunks for w3).
// Layer scales folded in (powers of 2: exact in bf16).

__global__ __launch_bounds__(256) void prep_weights(
    const float* __restrict__ w1, const float* __restrict__ w2,
    const float* __restrict__ w3,
    __bf16* __restrict__ w1t, __bf16* __restrict__ w2t, __bf16* __restrict__ w3t)
{
    const int t = threadIdx.x;
    for (int id = t; id < 4096; id += 256) {
        int j = id & 7, f = id >> 3;
        int lane = f & 63, g = f >> 6;         // g = c*2+s
        int c = g >> 1, s = g & 1;
        int n = c * 16 + (lane & 15);
        int k = s * 32 + (lane >> 4) * 8 + j;
        w1t[id] = (__bf16)(w1[k * 64 + n] * 0.125f);
        w2t[id] = (__bf16)(w2[k * 64 + n] * 0.125f);
    }
    for (int id = t; id < 16384; id += 256) {
        int j = id & 7, f = id >> 3;
        int lane = f & 63, g = f >> 6;         // g = ((w*4+c)*2+s)
        int wch = g >> 3, c = (g >> 1) & 3, s = g & 1;
        int n = wch * 64 + c * 16 + (lane & 15);
        int k = s * 32 + (lane >> 4) * 8 + j;
        w3t[id] = (__bf16)(w3[k * 256 + n] * 0.03125f);  // 1/8 * 1/sqrt(16)
    }
}

// ---------------- MFMA MLP: 64 edges per 256-thread block ----------------

__global__ __launch_bounds__(256, 3) void mlp_mfma(
    const float* __restrict__ ea,
    const int*   __restrict__ snd,
    const int*   __restrict__ perm,
    int*         __restrict__ ssort,
    float4*      __restrict__ evq,
    unsigned short* __restrict__ mixb,   // (E,256) bf16
    const float* __restrict__ w0,
    const __bf16* __restrict__ w1t,
    const __bf16* __restrict__ w2t,
    const __bf16* __restrict__ w3t,
    int E)
{
    __shared__ __bf16 hA[64 * HP];
    __shared__ __bf16 hB[64 * HP];
    __shared__ __bf16 mixs[64 * MIXP];

    const int t = threadIdx.x;
    const int lane = t & 63;
    const int wv = t >> 6;
    const int quad = lane >> 4;
    const int l15 = lane & 15;
    const int pbase = blockIdx.x * 64;

    // ---- layer 0 (8 -> 64), scalar fp32, silu, -> bf16 LDS
    {
        const int i = t >> 2;                 // edge slot 0..63
        const int jg = t & 3;                 // output group of 16
        const int p = pbase + i;
        const int pc = p < E ? p : E - 1;
        const int e = perm[pc];
        const float* ar = ea + (size_t)e * 11;
        float es[8];
        #pragma unroll
        for (int k = 0; k < 8; k++) es[k] = ar[k];
        if (p < E) {
            if (jg == 0) ssort[p] = snd[e];
            if (jg == 1) evq[p] = make_float4(ar[8], ar[9], ar[10], 0.f);
        }
        union { __bf16 hb[16]; uint4 q[2]; } u;
        #pragma unroll
        for (int jj = 0; jj < 16; jj++) {
            int j = jg * 16 + jj;
            float a = 0.f;
            #pragma unroll
            for (int k = 0; k < 8; k++) a += es[k] * w0[k * 64 + j];
            u.hb[jj] = (__bf16)silu_n(a * 0.35355339f);
        }
        uint4* dst = (uint4*)&hA[i * HP + jg * 16];
        dst[0] = u.q[0]; dst[1] = u.q[1];
    }
    // No barrier: wave wv wrote rows 16wv..16wv+15 and only reads those rows
    // through layers 1-2 (compiler inserts the lgkmcnt waits).

    auto layer = [&](const __bf16* src, __bf16* dst, const __bf16* wt) {
        const int m0 = wv * 16;
        const __bf16* arow = src + (m0 + l15) * HP;
        bf16x8 A0 = *(const bf16x8*)(arow + quad * 8);         // kstep 0
        bf16x8 A1 = *(const bf16x8*)(arow + 32 + quad * 8);    // kstep 1
        #pragma unroll
        for (int c = 0; c < 4; c++) {
            bf16x8 B0 = *(const bf16x8*)(wt + ((c * 2 + 0) * 64 + lane) * 8);
            bf16x8 B1 = *(const bf16x8*)(wt + ((c * 2 + 1) * 64 + lane) * 8);
            f32x4 a = {0.f, 0.f, 0.f, 0.f};
            a = __builtin_amdgcn_mfma_f32_16x16x32_bf16(A0, B0, a, 0, 0, 0);
            a = __builtin_amdgcn_mfma_f32_16x16x32_bf16(A1, B1, a, 0, 0, 0);
            #pragma unroll
            for (int r = 0; r < 4; r++) {
                // D: col = l15, row = quad*4 + r  (scale folded into weights)
                dst[(m0 + quad * 4 + r) * HP + c * 16 + l15] = (__bf16)silu_n(a[r]);
            }
        }
    };

    layer(hA, hB, w1t);   // layer 1
    layer(hB, hA, w2t);   // layer 2

    __syncthreads();      // layer 3: each wave needs ALL rows

    // ---- layer 3 (64 -> 256): wave wv owns col chunk [64wv, 64wv+64)
    {
        bf16x8 B[4][2];
        #pragma unroll
        for (int c = 0; c < 4; c++)
            #pragma unroll
            for (int s = 0; s < 2; s++)
                B[c][s] = *(const bf16x8*)(w3t + ((((wv * 4 + c) * 2) + s) * 64 + lane) * 8);

        f32x4 acc[4][4];
        #pragma unroll
        for (int m = 0; m < 4; m++)
            #pragma unroll
            for (int c = 0; c < 4; c++)
                acc[m][c] = (f32x4){0.f, 0.f, 0.f, 0.f};

        #pragma unroll
        for (int m = 0; m < 4; m++) {
            const __bf16* arow = hA + (m * 16 + l15) * HP;
            bf16x8 A0 = *(const bf16x8*)(arow + quad * 8);
            bf16x8 A1 = *(const bf16x8*)(arow + 32 + quad * 8);
            #pragma unroll
            for (int c = 0; c < 4; c++) {
                acc[m][c] = __builtin_amdgcn_mfma_f32_16x16x32_bf16(A0, B[c][0], acc[m][c], 0, 0, 0);
                acc[m][c] = __builtin_amdgcn_mfma_f32_16x16x32_bf16(A1, B[c][1], acc[m][c], 0, 0, 0);
            }
        }
        #pragma unroll
        for (int m = 0; m < 4; m++)
            #pragma unroll
            for (int c = 0; c < 4; c++)
                #pragma unroll
                for (int r = 0; r < 4; r++)
                    mixs[(m * 16 + quad * 4 + r) * MIXP + wv * 64 + c * 16 + l15] =
                        (__bf16)acc[m][c][r];
    }

    __syncthreads();

    // ---- coalesced copy-out: 64 rows x 256 bf16
    #pragma unroll
    for (int u = 0; u < 8; u++) {
        int c2 = u * 256 + t;          // 0..2047 chunks of 8 bf16
        int row = c2 >> 5;
        int col8 = c2 & 31;
        if (pbase + row < E) {
            uint4 v = *(const uint4*)&mixs[row * MIXP + col8 * 8];
            *(uint4*)(mixb + ((size_t)(pbase + row)) * 256 + col8 * 8) = v;
        }
    }
}

// ---------------- kernel B: one wave per node, CSR walk, zero atomics ----------------

__global__ __launch_bounds__(64) void gather_nodes(
    const float* __restrict__ nf,
    const int*   __restrict__ offs,
    const int*   __restrict__ ssort,
    const float4* __restrict__ evq,
    const unsigned short* __restrict__ mixb,
    float* __restrict__ out)
{
    const int n = blockIdx.x;
    const int lane = threadIdx.x;
    const int p0 = offs[n], p1 = offs[n + 1];

    float s1 = 0.f, s2 = 0.f;
    float a10 = 0.f, a11 = 0.f, a12 = 0.f;
    float a20 = 0.f, a21 = 0.f, a22 = 0.f;

    for (int p = p0; p < p1; p++) {
        const int s = ssort[p];
        const float4 ev = evq[p];
        const unsigned short* mr = mixb + (size_t)p * 256;
        float m0 = b2f(mr[lane]);
        float m1 = b2f(mr[64 + lane]);
        float m2 = b2f(mr[128 + lane]);
        float m3 = b2f(mr[192 + lane]);
        const float* nrow = nf + (size_t)s * 256;
        float sv = nrow[lane];
        const float* vr = nrow + 64 + 3 * lane;
        float v0 = vr[0], v1 = vr[1], v2 = vr[2];

        s1 += sv * m0;
        s2 += (v0 * ev.x + v1 * ev.y + v2 * ev.z) * m1;
        a10 += v0 * m2; a11 += v1 * m2; a12 += v2 * m2;
        float tt = sv * m3;
        a20 += tt * ev.x; a21 += tt * ev.y; a22 += tt * ev.z;
    }

    float* orow = out + (size_t)n * 512;
    orow[lane] = s1;
    orow[64 + lane] = s2 * 0.57735027f;
    float* o1 = orow + 128 + 3 * lane;
    o1[0] = a10; o1[1] = a11; o1[2] = a12;
    float* o2 = orow + 320 + 3 * lane;
    o2[0] = a20; o2[1] = a21; o2[2] = a22;
}

// ---------------- fallback (atomic fused kernel) if ws too small ----------------

#define BLOCK 128
__device__ __forceinline__ void atomAddF(float* p, float v) { unsafeAtomicAdd(p, v); }

__global__ void __launch_bounds__(BLOCK) fused_mp(
    const float* __restrict__ nf, const float* __restrict__ ea,
    const int* __restrict__ snd, const int* __restrict__ rcv,
    const float* __restrict__ w0, const float* __restrict__ w1,
    const float* __restrict__ w2, const float* __restrict__ w3,
    float* __restrict__ out, int E)
{
    __shared__ float lds_h[BLOCK * 64];
    __shared__ float lds_st[BLOCK * 64];
    const int tid = threadIdx.x;
    const int lane = tid & 63;
    const int wv = tid >> 6;
    const int ebase = blockIdx.x * BLOCK;
    const int e = ebase + tid;
    const bool valid = e < E;

    float es[8];
    float ev0 = 0.f, ev1 = 0.f, ev2 = 0.f;
    int sidx = 0, ridx = 0;
    if (valid) {
        const float* p = ea + (size_t)e * 11;
        #pragma unroll
        for (int k = 0; k < 8; k++) es[k] = p[k];
        ev0 = p[8]; ev1 = p[9]; ev2 = p[10];
        sidx = snd[e]; ridx = rcv[e];
    } else {
        #pragma unroll
        for (int k = 0; k < 8; k++) es[k] = 0.f;
    }
    for (int j = 0; j < 64; j++) {
        float a = 0.f;
        #pragma unroll
        for (int k = 0; k < 8; k++) a += es[k] * w0[k * 64 + j];
        lds_h[j * BLOCK + tid] = silu_n(a * 0.35355339f);
    }
    float acc[64];
    #pragma unroll
    for (int j = 0; j < 64; j++) acc[j] = 0.f;
    for (int k = 0; k < 64; k++) {
        float hk = lds_h[k * BLOCK + tid];
        const float* wr = w1 + k * 64;
        #pragma unroll
        for (int j = 0; j < 64; j++) acc[j] += hk * wr[j];
    }
    #pragma unroll
    for (int j = 0; j < 64; j++) lds_h[j * BLOCK + tid] = silu_n(acc[j] * 0.125f);
    #pragma unroll
    for (int j = 0; j < 64; j++) acc[j] = 0.f;
    for (int k = 0; k < 64; k++) {
        float hk = lds_h[k * BLOCK + tid];
        const float* wr = w2 + k * 64;
        #pragma unroll
        for (int j = 0; j < 64; j++) acc[j] += hk * wr[j];
    }
    #pragma unroll
    for (int j = 0; j < 64; j++) lds_h[j * BLOCK + tid] = silu_n(acc[j] * 0.125f);

    const int wave_base = ebase + wv * 64;
    int wn = E - wave_base;
    const int wave_nvalid = wn < 0 ? 0 : (wn > 64 ? 64 : wn);
    float* st = lds_st + wv * 64 * 64;

    auto compute_chunk = [&](int c) {
        #pragma unroll
        for (int j = 0; j < 64; j++) acc[j] = 0.f;
        for (int k = 0; k < 64; k++) {
            float hk = lds_h[k * BLOCK + tid];
            const float* wr = w3 + k * 256 + c * 64;
            #pragma unroll
            for (int j = 0; j < 64; j++) acc[j] += hk * wr[j];
        }
        #pragma unroll
        for (int j = 0; j < 64; j++) st[j * 64 + (lane ^ j)] = acc[j] * (0.125f * 0.25f);
    };

    compute_chunk(0);
    for (int i = 0; i < wave_nvalid; i++) {
        int sI = __shfl(sidx, i);
        int rI = __shfl(ridx, i);
        float m = st[lane * 64 + (i ^ lane)];
        atomAddF(&out[(size_t)rI * 512 + lane], nf[(size_t)sI * 256 + lane] * m);
    }
    compute_chunk(1);
    for (int i = 0; i < wave_nvalid; i++) {
        int sI = __shfl(sidx, i);
        int rI = __shfl(ridx, i);
        float a0 = __shfl(ev0, i), a1 = __shfl(ev1, i), a2 = __shfl(ev2, i);
        const float* vr = nf + (size_t)sI * 256 + 64 + 3 * lane;
        float d = vr[0] * a0 + vr[1] * a1 + vr[2] * a2;
        float m = st[lane * 64 + (i ^ lane)];
        atomAddF(&out[(size_t)rI * 512 + 64 + lane], d * 0.57735027f * m);
    }
    compute_chunk(2);
    for (int i = 0; i < wave_nvalid; i++) {
        int sI = __shfl(sidx, i);
        int rI = __shfl(ridx, i);
        const float* vr = nf + (size_t)sI * 256 + 64 + 3 * lane;
        float m = st[lane * 64 + (i ^ lane)];
        float* orow = out + (size_t)rI * 512 + 128 + 3 * lane;
        atomAddF(orow + 0, vr[0] * m);
        atomAddF(orow + 1, vr[1] * m);
        atomAddF(orow + 2, vr[2] * m);
    }
    compute_chunk(3);
    for (int i = 0; i < wave_nvalid; i++) {
        int sI = __shfl(sidx, i);
        int rI = __shfl(ridx, i);
        float a0 = __shfl(ev0, i), a1 = __shfl(ev1, i), a2 = __shfl(ev2, i);
        float sv = nf[(size_t)sI * 256 + lane];
        float m = st[lane * 64 + (i ^ lane)];
        float* orow = out + (size_t)rI * 512 + 320 + 3 * lane;
        atomAddF(orow + 0, sv * a0 * m);
        atomAddF(orow + 1, sv * a1 * m);
        atomAddF(orow + 2, sv * a2 * m);
    }
}

// ---------------- launch ----------------

static inline size_t al256(size_t x) { return (x + 255) & ~(size_t)255; }

extern "C" void kernel_launch(void* const* d_in, const int* in_sizes, int n_in,
                              void* d_out, int out_size, void* d_ws, size_t ws_size,
                              hipStream_t stream)
{
    const float* nf = (const float*)d_in[0];
    const float* ea = (const float*)d_in[1];
    const int*   sn = (const int*)  d_in[2];
    const int*   rc = (const int*)  d_in[3];
    const float* w0 = (const float*)d_in[4];
    const float* w1 = (const float*)d_in[5];
    const float* w2 = (const float*)d_in[6];
    const float* w3 = (const float*)d_in[7];
    float* out = (float*)d_out;
    const int E = in_sizes[2];
    const int N = in_sizes[0] / 256;

    size_t o_cnt  = 0;
    size_t o_offs = o_cnt  + al256((size_t)(N + 1) * 4);
    size_t o_wptr = o_offs + al256((size_t)(N + 1) * 4);
    size_t o_perm = o_wptr + al256((size_t)N * 4);
    size_t o_ssrt = o_perm + al256((size_t)E * 4);
    size_t o_evq  = o_ssrt + al256((size_t)E * 4);
    size_t o_mix  = o_evq  + al256((size_t)E * 16);
    size_t o_w1t  = o_mix  + al256((size_t)E * 512);
    size_t o_w2t  = o_w1t  + al256(4096 * 2);
    size_t o_w3t  = o_w2t  + al256(4096 * 2);
    size_t need   = o_w3t  + 16384 * 2;

    if (ws_size < need) {
        hipMemsetAsync(d_out, 0, (size_t)out_size * sizeof(float), stream);
        const int blocks = (E + BLOCK - 1) / BLOCK;
        fused_mp<<<blocks, BLOCK, 0, stream>>>(nf, ea, sn, rc, w0, w1, w2, w3, out, E);
        return;
    }

    char* ws = (char*)d_ws;
    int* cnt  = (int*)(ws + o_cnt);
    int* offs = (int*)(ws + o_offs);
    int* wptr = (int*)(ws + o_wptr);
    int* perm = (int*)(ws + o_perm);
    int* ssrt = (int*)(ws + o_ssrt);
    float4* evq = (float4*)(ws + o_evq);
    unsigned short* mixb = (unsigned short*)(ws + o_mix);
    __bf16* w1t = (__bf16*)(ws + o_w1t);
    __bf16* w2t = (__bf16*)(ws + o_w2t);
    __bf16* w3t = (__bf16*)(ws + o_w3t);

    hipMemsetAsync(cnt, 0, (size_t)(N + 1) * 4, stream);
    prep_weights<<<1, 256, 0, stream>>>(w1, w2, w3, w1t, w2t, w3t);
    hist_kernel<<<(E + 255) / 256, 256, 0, stream>>>(rc, cnt, E);
    scan_kernel<<<1, 1024, 0, stream>>>(cnt, offs, wptr, N, E);
    scatter_kernel<<<(E + 255) / 256, 256, 0, stream>>>(rc, wptr, perm, E);
    mlp_mfma<<<(E + 63) / 64, 256, 0, stream>>>(
        ea, sn, perm, ssrt, evq, mixb, w0, w1t, w2t, w3t, E);
    gather_nodes<<<N, 64, 0, stream>>>(nf, offs, ssrt, evq, mixb, out);
}

// Round 6
// 325.537 us; speedup vs baseline: 5.9236x; 1.0109x over previous
//
#include <hip/hip_runtime.h>

typedef __attribute__((ext_vector_type(8))) __bf16 bf16x8;
typedef __attribute__((ext_vector_type(4))) float f32x4;

#define HP 72      // padded bf16 per hidden row (144 B, 16B-aligned, 2-way-bank only)
#define MIXP 264   // padded bf16 per mix staging row (528 B)

// E[silu(Z)^2] over N(0,1) = 0.3557704 -> 1/sqrt = 1.6765444 (ACT_CST)
__device__ __forceinline__ float silu_n(float x) {
    return x / (1.0f + __expf(-x)) * 1.6765444f;
}

__device__ __forceinline__ unsigned short f2b(float f) {
    unsigned int u = __float_as_uint(f);
    u += 0x7FFF + ((u >> 16) & 1);
    return (unsigned short)(u >> 16);
}
__device__ __forceinline__ float b2f(unsigned short u) {
    return __uint_as_float(((unsigned int)u) << 16);
}

// ---------------- sort-by-receiver infrastructure (verified r2/r3) ----------------

__global__ void hist_kernel(const int* __restrict__ rcv, int* __restrict__ cnt, int E) {
    int e = blockIdx.x * blockDim.x + threadIdx.x;
    if (e < E) atomicAdd(&cnt[rcv[e]], 1);
}

__global__ __launch_bounds__(1024) void scan_kernel(
    const int* __restrict__ cnt, int* __restrict__ offs, int* __restrict__ wptr,
    int N, int E)
{
    __shared__ int sd[1024];
    const int tid = threadIdx.x;
    const int C = (N + 1023) >> 10;
    const int b = tid * C;
    const int en = min(b + C, N);
    int sum = 0;
    for (int i = b; i < en; i++) sum += cnt[i];
    sd[tid] = sum;
    __syncthreads();
    for (int off = 1; off < 1024; off <<= 1) {
        int t = (tid >= off) ? sd[tid - off] : 0;
        __syncthreads();
        sd[tid] += t;
        __syncthreads();
    }
    int run = sd[tid] - sum;
    for (int i = b; i < en; i++) {
        offs[i] = run; wptr[i] = run;
        run += cnt[i];
    }
    if (tid == 0) offs[N] = E;
}

__global__ void scatter_kernel(const int* __restrict__ rcv, int* __restrict__ wptr,
                               int* __restrict__ perm, int E) {
    int e = blockIdx.x * blockDim.x + threadIdx.x;
    if (e < E) {
        int p = atomicAdd(&wptr[rcv[e]], 1);
        perm[p] = e;
    }
}

// ---------------- weight pre-swizzle into MFMA B-fragment order (verified r3) ----------------

__global__ __launch_bounds__(256) void prep_weights(
    const float* __restrict__ w1, const float* __restrict__ w2,
    const float* __restrict__ w3,
    __bf16* __restrict__ w1t, __bf16* __restrict__ w2t, __bf16* __restrict__ w3t)
{
    const int t = threadIdx.x;
    for (int id = t; id < 4096; id += 256) {
        int j = id & 7, f = id >> 3;
        int lane = f & 63, g = f >> 6;         // g = c*2+s
        int c = g >> 1, s = g & 1;
        int n = c * 16 + (lane & 15);
        int k = s * 32 + (lane >> 4) * 8 + j;
        w1t[id] = (__bf16)(w1[k * 64 + n] * 0.125f);
        w2t[id] = (__bf16)(w2[k * 64 + n] * 0.125f);
    }
    for (int id = t; id < 16384; id += 256) {
        int j = id & 7, f = id >> 3;
        int lane = f & 63, g = f >> 6;         // g = ((w*4+c)*2+s)
        int wch = g >> 3, c = (g >> 1) & 3, s = g & 1;
        int n = wch * 64 + c * 16 + (lane & 15);
        int k = s * 32 + (lane >> 4) * 8 + j;
        w3t[id] = (__bf16)(w3[k * 256 + n] * 0.03125f);  // 1/8 * 1/sqrt(16)
    }
}

// ---------------- MFMA MLP: 64 edges per 256-thread block (verified r3, verbatim) ----------------

__global__ __launch_bounds__(256, 3) void mlp_mfma(
    const float* __restrict__ ea,
    const int*   __restrict__ snd,
    const int*   __restrict__ perm,
    int*         __restrict__ ssort,
    float4*      __restrict__ evq,
    unsigned short* __restrict__ mixb,   // (E,256) bf16
    const float* __restrict__ w0,
    const __bf16* __restrict__ w1t,
    const __bf16* __restrict__ w2t,
    const __bf16* __restrict__ w3t,
    int E)
{
    __shared__ __bf16 hA[64 * HP];
    __shared__ __bf16 hB[64 * HP];
    __shared__ __bf16 mixs[64 * MIXP];

    const int t = threadIdx.x;
    const int lane = t & 63;
    const int wv = t >> 6;
    const int quad = lane >> 4;
    const int l15 = lane & 15;
    const int pbase = blockIdx.x * 64;

    // ---- layer 0 (8 -> 64), scalar fp32, silu, -> bf16 LDS
    {
        const int i = t >> 2;                 // edge slot 0..63
        const int jg = t & 3;                 // output group of 16
        const int p = pbase + i;
        const int pc = p < E ? p : E - 1;
        const int e = perm[pc];
        const float* ar = ea + (size_t)e * 11;
        float es[8];
        #pragma unroll
        for (int k = 0; k < 8; k++) es[k] = ar[k];
        if (p < E) {
            if (jg == 0) ssort[p] = snd[e];
            if (jg == 1) evq[p] = make_float4(ar[8], ar[9], ar[10], 0.f);
        }
        union { __bf16 hb[16]; uint4 q[2]; } u;
        #pragma unroll
        for (int jj = 0; jj < 16; jj++) {
            int j = jg * 16 + jj;
            float a = 0.f;
            #pragma unroll
            for (int k = 0; k < 8; k++) a += es[k] * w0[k * 64 + j];
            u.hb[jj] = (__bf16)silu_n(a * 0.35355339f);
        }
        uint4* dst = (uint4*)&hA[i * HP + jg * 16];
        dst[0] = u.q[0]; dst[1] = u.q[1];
    }
    // No barrier: wave wv wrote rows 16wv..16wv+15 and only reads those rows
    // through layers 1-2 (compiler inserts the lgkmcnt waits).

    auto layer = [&](const __bf16* src, __bf16* dst, const __bf16* wt) {
        const int m0 = wv * 16;
        const __bf16* arow = src + (m0 + l15) * HP;
        bf16x8 A0 = *(const bf16x8*)(arow + quad * 8);         // kstep 0
        bf16x8 A1 = *(const bf16x8*)(arow + 32 + quad * 8);    // kstep 1
        #pragma unroll
        for (int c = 0; c < 4; c++) {
            bf16x8 B0 = *(const bf16x8*)(wt + ((c * 2 + 0) * 64 + lane) * 8);
            bf16x8 B1 = *(const bf16x8*)(wt + ((c * 2 + 1) * 64 + lane) * 8);
            f32x4 a = {0.f, 0.f, 0.f, 0.f};
            a = __builtin_amdgcn_mfma_f32_16x16x32_bf16(A0, B0, a, 0, 0, 0);
            a = __builtin_amdgcn_mfma_f32_16x16x32_bf16(A1, B1, a, 0, 0, 0);
            #pragma unroll
            for (int r = 0; r < 4; r++) {
                // D: col = l15, row = quad*4 + r  (scale folded into weights)
                dst[(m0 + quad * 4 + r) * HP + c * 16 + l15] = (__bf16)silu_n(a[r]);
            }
        }
    };

    layer(hA, hB, w1t);   // layer 1
    layer(hB, hA, w2t);   // layer 2

    __syncthreads();      // layer 3: each wave needs ALL rows

    // ---- layer 3 (64 -> 256): wave wv owns col chunk [64wv, 64wv+64)
    {
        bf16x8 B[4][2];
        #pragma unroll
        for (int c = 0; c < 4; c++)
            #pragma unroll
            for (int s = 0; s < 2; s++)
                B[c][s] = *(const bf16x8*)(w3t + ((((wv * 4 + c) * 2) + s) * 64 + lane) * 8);

        f32x4 acc[4][4];
        #pragma unroll
        for (int m = 0; m < 4; m++)
            #pragma unroll
            for (int c = 0; c < 4; c++)
                acc[m][c] = (f32x4){0.f, 0.f, 0.f, 0.f};

        #pragma unroll
        for (int m = 0; m < 4; m++) {
            const __bf16* arow = hA + (m * 16 + l15) * HP;
            bf16x8 A0 = *(const bf16x8*)(arow + quad * 8);
            bf16x8 A1 = *(const bf16x8*)(arow + 32 + quad * 8);
            #pragma unroll
            for (int c = 0; c < 4; c++) {
                acc[m][c] = __builtin_amdgcn_mfma_f32_16x16x32_bf16(A0, B[c][0], acc[m][c], 0, 0, 0);
                acc[m][c] = __builtin_amdgcn_mfma_f32_16x16x32_bf16(A1, B[c][1], acc[m][c], 0, 0, 0);
            }
        }
        #pragma unroll
        for (int m = 0; m < 4; m++)
            #pragma unroll
            for (int c = 0; c < 4; c++)
                #pragma unroll
                for (int r = 0; r < 4; r++)
                    mixs[(m * 16 + quad * 4 + r) * MIXP + wv * 64 + c * 16 + l15] =
                        (__bf16)acc[m][c][r];
    }

    __syncthreads();

    // ---- coalesced copy-out: 64 rows x 256 bf16
    #pragma unroll
    for (int u = 0; u < 8; u++) {
        int c2 = u * 256 + t;          // 0..2047 chunks of 8 bf16
        int row = c2 >> 5;
        int col8 = c2 & 31;
        if (pbase + row < E) {
            uint4 v = *(const uint4*)&mixs[row * MIXP + col8 * 8];
            *(uint4*)(mixb + ((size_t)(pbase + row)) * 256 + col8 * 8) = v;
        }
    }
}

// ---------------- kernel B: 4 waves per node, CSR walk, LDS reduce, zero atomics ----------------

__global__ __launch_bounds__(256) void gather_nodes4(
    const float* __restrict__ nf,
    const int*   __restrict__ offs,
    const int*   __restrict__ ssort,
    const float4* __restrict__ evq,
    const unsigned short* __restrict__ mixb,
    float* __restrict__ out)
{
    __shared__ float red[4][8][64];

    const int n = blockIdx.x;
    const int t = threadIdx.x;
    const int lane = t & 63;
    const int wv = t >> 6;
    const int p0 = offs[n], p1 = offs[n + 1];

    float s1 = 0.f, s2 = 0.f;
    float a10 = 0.f, a11 = 0.f, a12 = 0.f;
    float a20 = 0.f, a21 = 0.f, a22 = 0.f;

    for (int p = p0 + wv; p < p1; p += 4) {
        const int s = ssort[p];
        const float4 ev = evq[p];
        const unsigned short* mr = mixb + (size_t)p * 256;
        float m0 = b2f(mr[lane]);
        float m1 = b2f(mr[64 + lane]);
        float m2 = b2f(mr[128 + lane]);
        float m3 = b2f(mr[192 + lane]);
        const float* nrow = nf + (size_t)s * 256;
        float sv = nrow[lane];
        const float* vr = nrow + 64 + 3 * lane;
        float v0 = vr[0], v1 = vr[1], v2 = vr[2];

        s1 += sv * m0;
        s2 += (v0 * ev.x + v1 * ev.y + v2 * ev.z) * m1;
        a10 += v0 * m2; a11 += v1 * m2; a12 += v2 * m2;
        float tt = sv * m3;
        a20 += tt * ev.x; a21 += tt * ev.y; a22 += tt * ev.z;
    }

    red[wv][0][lane] = s1;  red[wv][1][lane] = s2;
    red[wv][2][lane] = a10; red[wv][3][lane] = a11; red[wv][4][lane] = a12;
    red[wv][5][lane] = a20; red[wv][6][lane] = a21; red[wv][7][lane] = a22;
    __syncthreads();

    if (wv == 0) {
        float r[8];
        #pragma unroll
        for (int c = 0; c < 8; c++)
            r[c] = red[0][c][lane] + red[1][c][lane] + red[2][c][lane] + red[3][c][lane];
        float* orow = out + (size_t)n * 512;
        orow[lane] = r[0];
        orow[64 + lane] = r[1] * 0.57735027f;   // INV_SQRT3 applied once
        float* o1 = orow + 128 + 3 * lane;
        o1[0] = r[2]; o1[1] = r[3]; o1[2] = r[4];
        float* o2 = orow + 320 + 3 * lane;
        o2[0] = r[5]; o2[1] = r[6]; o2[2] = r[7];
    }
}

// ---------------- fallback (atomic fused kernel) if ws too small ----------------

#define BLOCK 128
__device__ __forceinline__ void atomAddF(float* p, float v) { unsafeAtomicAdd(p, v); }

__global__ void __launch_bounds__(BLOCK) fused_mp(
    const float* __restrict__ nf, const float* __restrict__ ea,
    const int* __restrict__ snd, const int* __restrict__ rcv,
    const float* __restrict__ w0, const float* __restrict__ w1,
    const float* __restrict__ w2, const float* __restrict__ w3,
    float* __restrict__ out, int E)
{
    __shared__ float lds_h[BLOCK * 64];
    __shared__ float lds_st[BLOCK * 64];
    const int tid = threadIdx.x;
    const int lane = tid & 63;
    const int wv = tid >> 6;
    const int ebase = blockIdx.x * BLOCK;
    const int e = ebase + tid;
    const bool valid = e < E;

    float es[8];
    float ev0 = 0.f, ev1 = 0.f, ev2 = 0.f;
    int sidx = 0, ridx = 0;
    if (valid) {
        const float* p = ea + (size_t)e * 11;
        #pragma unroll
        for (int k = 0; k < 8; k++) es[k] = p[k];
        ev0 = p[8]; ev1 = p[9]; ev2 = p[10];
        sidx = snd[e]; ridx = rcv[e];
    } else {
        #pragma unroll
        for (int k = 0; k < 8; k++) es[k] = 0.f;
    }
    for (int j = 0; j < 64; j++) {
        float a = 0.f;
        #pragma unroll
        for (int k = 0; k < 8; k++) a += es[k] * w0[k * 64 + j];
        lds_h[j * BLOCK + tid] = silu_n(a * 0.35355339f);
    }
    float acc[64];
    #pragma unroll
    for (int j = 0; j < 64; j++) acc[j] = 0.f;
    for (int k = 0; k < 64; k++) {
        float hk = lds_h[k * BLOCK + tid];
        const float* wr = w1 + k * 64;
        #pragma unroll
        for (int j = 0; j < 64; j++) acc[j] += hk * wr[j];
    }
    #pragma unroll
    for (int j = 0; j < 64; j++) lds_h[j * BLOCK + tid] = silu_n(acc[j] * 0.125f);
    #pragma unroll
    for (int j = 0; j < 64; j++) acc[j] = 0.f;
    for (int k = 0; k < 64; k++) {
        float hk = lds_h[k * BLOCK + tid];
        const float* wr = w2 + k * 64;
        #pragma unroll
        for (int j = 0; j < 64; j++) acc[j] += hk * wr[j];
    }
    #pragma unroll
    for (int j = 0; j < 64; j++) lds_h[j * BLOCK + tid] = silu_n(acc[j] * 0.125f);

    const int wave_base = ebase + wv * 64;
    int wn = E - wave_base;
    const int wave_nvalid = wn < 0 ? 0 : (wn > 64 ? 64 : wn);
    float* st = lds_st + wv * 64 * 64;

    auto compute_chunk = [&](int c) {
        #pragma unroll
        for (int j = 0; j < 64; j++) acc[j] = 0.f;
        for (int k = 0; k < 64; k++) {
            float hk = lds_h[k * BLOCK + tid];
            const float* wr = w3 + k * 256 + c * 64;
            #pragma unroll
            for (int j = 0; j < 64; j++) acc[j] += hk * wr[j];
        }
        #pragma unroll
        for (int j = 0; j < 64; j++) st[j * 64 + (lane ^ j)] = acc[j] * (0.125f * 0.25f);
    };

    compute_chunk(0);
    for (int i = 0; i < wave_nvalid; i++) {
        int sI = __shfl(sidx, i);
        int rI = __shfl(ridx, i);
        float m = st[lane * 64 + (i ^ lane)];
        atomAddF(&out[(size_t)rI * 512 + lane], nf[(size_t)sI * 256 + lane] * m);
    }
    compute_chunk(1);
    for (int i = 0; i < wave_nvalid; i++) {
        int sI = __shfl(sidx, i);
        int rI = __shfl(ridx, i);
        float a0 = __shfl(ev0, i), a1 = __shfl(ev1, i), a2 = __shfl(ev2, i);
        const float* vr = nf + (size_t)sI * 256 + 64 + 3 * lane;
        float d = vr[0] * a0 + vr[1] * a1 + vr[2] * a2;
        float m = st[lane * 64 + (i ^ lane)];
        atomAddF(&out[(size_t)rI * 512 + 64 + lane], d * 0.57735027f * m);
    }
    compute_chunk(2);
    for (int i = 0; i < wave_nvalid; i++) {
        int sI = __shfl(sidx, i);
        int rI = __shfl(ridx, i);
        const float* vr = nf + (size_t)sI * 256 + 64 + 3 * lane;
        float m = st[lane * 64 + (i ^ lane)];
        float* orow = out + (size_t)rI * 512 + 128 + 3 * lane;
        atomAddF(orow + 0, vr[0] * m);
        atomAddF(orow + 1, vr[1] * m);
        atomAddF(orow + 2, vr[2] * m);
    }
    compute_chunk(3);
    for (int i = 0; i < wave_nvalid; i++) {
        int sI = __shfl(sidx, i);
        int rI = __shfl(ridx, i);
        float a0 = __shfl(ev0, i), a1 = __shfl(ev1, i), a2 = __shfl(ev2, i);
        float sv = nf[(size_t)sI * 256 + lane];
        float m = st[lane * 64 + (i ^ lane)];
        float* orow = out + (size_t)rI * 512 + 320 + 3 * lane;
        atomAddF(orow + 0, sv * a0 * m);
        atomAddF(orow + 1, sv * a1 * m);
        atomAddF(orow + 2, sv * a2 * m);
    }
}

// ---------------- launch ----------------

static inline size_t al256(size_t x) { return (x + 255) & ~(size_t)255; }

extern "C" void kernel_launch(void* const* d_in, const int* in_sizes, int n_in,
                              void* d_out, int out_size, void* d_ws, size_t ws_size,
                              hipStream_t stream)
{
    const float* nf = (const float*)d_in[0];
    const float* ea = (const float*)d_in[1];
    const int*   sn = (const int*)  d_in[2];
    const int*   rc = (const int*)  d_in[3];
    const float* w0 = (const float*)d_in[4];
    const float* w1 = (const float*)d_in[5];
    const float* w2 = (const float*)d_in[6];
    const float* w3 = (const float*)d_in[7];
    float* out = (float*)d_out;
    const int E = in_sizes[2];
    const int N = in_sizes[0] / 256;

    size_t o_cnt  = 0;
    size_t o_offs = o_cnt  + al256((size_t)(N + 1) * 4);
    size_t o_wptr = o_offs + al256((size_t)(N + 1) * 4);
    size_t o_perm = o_wptr + al256((size_t)N * 4);
    size_t o_ssrt = o_perm + al256((size_t)E * 4);
    size_t o_evq  = o_ssrt + al256((size_t)E * 4);
    size_t o_mix  = o_evq  + al256((size_t)E * 16);
    size_t o_w1t  = o_mix  + al256((size_t)E * 512);
    size_t o_w2t  = o_w1t  + al256(4096 * 2);
    size_t o_w3t  = o_w2t  + al256(4096 * 2);
    size_t need   = o_w3t  + 16384 * 2;

    if (ws_size < need) {
        hipMemsetAsync(d_out, 0, (size_t)out_size * sizeof(float), stream);
        const int blocks = (E + BLOCK - 1) / BLOCK;
        fused_mp<<<blocks, BLOCK, 0, stream>>>(nf, ea, sn, rc, w0, w1, w2, w3, out, E);
        return;
    }

    char* ws = (char*)d_ws;
    int* cnt  = (int*)(ws + o_cnt);
    int* offs = (int*)(ws + o_offs);
    int* wptr = (int*)(ws + o_wptr);
    int* perm = (int*)(ws + o_perm);
    int* ssrt = (int*)(ws + o_ssrt);
    float4* evq = (float4*)(ws + o_evq);
    unsigned short* mixb = (unsigned short*)(ws + o_mix);
    __bf16* w1t = (__bf16*)(ws + o_w1t);
    __bf16* w2t = (__bf16*)(ws + o_w2t);
    __bf16* w3t = (__bf16*)(ws + o_w3t);

    hipMemsetAsync(cnt, 0, (size_t)(N + 1) * 4, stream);
    prep_weights<<<1, 256, 0, stream>>>(w1, w2, w3, w1t, w2t, w3t);
    hist_kernel<<<(E + 255) / 256, 256, 0, stream>>>(rc, cnt, E);
    scan_kernel<<<1, 1024, 0, stream>>>(cnt, offs, wptr, N, E);
    scatter_kernel<<<(E + 255) / 256, 256, 0, stream>>>(rc, wptr, perm, E);
    mlp_mfma<<<(E + 63) / 64, 256, 0, stream>>>(
        ea, sn, perm, ssrt, evq, mixb, w0, w1t, w2t, w3t, E);
    gather_nodes4<<<N, 256, 0, stream>>>(nf, offs, ssrt, evq, mixb, out);
}

// Round 7
// 324.193 us; speedup vs baseline: 5.9482x; 1.0041x over previous
//
#include <hip/hip_runtime.h>

typedef __attribute__((ext_vector_type(8))) __bf16 bf16x8;
typedef __attribute__((ext_vector_type(4))) float f32x4;

#define HP 72      // padded bf16 per hidden row (144 B, 16B-aligned, 2-way-bank only)
#define MIXP 264   // padded ushort per mix staging row (528 B)

// E[silu(Z)^2] over N(0,1) = 0.3557704 -> 1/sqrt = 1.6765444 (ACT_CST)
__device__ __forceinline__ float silu_n(float x) {
    return x / (1.0f + __expf(-x)) * 1.6765444f;
}

__device__ __forceinline__ unsigned short f2b(float f) {   // fp32 -> bf16 RNE
    unsigned int u = __float_as_uint(f);
    u += 0x7FFF + ((u >> 16) & 1);
    return (unsigned short)(u >> 16);
}
__device__ __forceinline__ float b2f(unsigned short u) {
    return __uint_as_float(((unsigned int)u) << 16);
}

// ---------------- sort-by-receiver infrastructure (verified r2/r3/r6) ----------------

__global__ void hist_kernel(const int* __restrict__ rcv, int* __restrict__ cnt, int E) {
    int e = blockIdx.x * blockDim.x + threadIdx.x;
    if (e < E) atomicAdd(&cnt[rcv[e]], 1);
}

__global__ __launch_bounds__(1024) void scan_kernel(
    const int* __restrict__ cnt, int* __restrict__ offs, int* __restrict__ wptr,
    int N, int E)
{
    __shared__ int sd[1024];
    const int tid = threadIdx.x;
    const int C = (N + 1023) >> 10;
    const int b = tid * C;
    const int en = min(b + C, N);
    int sum = 0;
    for (int i = b; i < en; i++) sum += cnt[i];
    sd[tid] = sum;
    __syncthreads();
    for (int off = 1; off < 1024; off <<= 1) {
        int t = (tid >= off) ? sd[tid - off] : 0;
        __syncthreads();
        sd[tid] += t;
        __syncthreads();
    }
    int run = sd[tid] - sum;
    for (int i = b; i < en; i++) {
        offs[i] = run; wptr[i] = run;
        run += cnt[i];
    }
    if (tid == 0) offs[N] = E;
}

__global__ void scatter_kernel(const int* __restrict__ rcv, int* __restrict__ wptr,
                               int* __restrict__ perm, int E) {
    int e = blockIdx.x * blockDim.x + threadIdx.x;
    if (e < E) {
        int p = atomicAdd(&wptr[rcv[e]], 1);
        perm[p] = e;
    }
}

// ---------------- weight pre-swizzle into MFMA B-fragment order (verified r3/r6) ----------------

__global__ __launch_bounds__(256) void prep_weights(
    const float* __restrict__ w1, const float* __restrict__ w2,
    const float* __restrict__ w3,
    __bf16* __restrict__ w1t, __bf16* __restrict__ w2t, __bf16* __restrict__ w3t)
{
    const int t = threadIdx.x;
    for (int id = t; id < 4096; id += 256) {
        int j = id & 7, f = id >> 3;
        int lane = f & 63, g = f >> 6;         // g = c*2+s
        int c = g >> 1, s = g & 1;
        int n = c * 16 + (lane & 15);
        int k = s * 32 + (lane >> 4) * 8 + j;
        w1t[id] = (__bf16)(w1[k * 64 + n] * 0.125f);
        w2t[id] = (__bf16)(w2[k * 64 + n] * 0.125f);
    }
    for (int id = t; id < 16384; id += 256) {
        int j = id & 7, f = id >> 3;
        int lane = f & 63, g = f >> 6;         // g = ((w*4+c)*2+s)
        int wch = g >> 3, c = (g >> 1) & 3, s = g & 1;
        int n = wch * 64 + c * 16 + (lane & 15);
        int k = s * 32 + (lane >> 4) * 8 + j;
        w3t[id] = (__bf16)(w3[k * 256 + n] * 0.03125f);  // 1/8 * 1/sqrt(16)
    }
}

// ---------------- MFMA MLP: 64 edges per 256-thread block ----------------
// r3/r6-verified compute; copy-out now stages 32 rows at a time (LDS 52K->35K,
// 4 blocks/CU) and writes mixb TRANSPOSED: [edge][lane][4] (ushort4 per lane).

__global__ __launch_bounds__(256, 4) void mlp_mfma(
    const float* __restrict__ ea,
    const int*   __restrict__ snd,
    const int*   __restrict__ perm,
    int*         __restrict__ ssort,
    float4*      __restrict__ evq,
    unsigned short* __restrict__ mixb,   // (E,64,4) bf16 bits, lane-major
    const float* __restrict__ w0,
    const __bf16* __restrict__ w1t,
    const __bf16* __restrict__ w2t,
    const __bf16* __restrict__ w3t,
    int E)
{
    __shared__ __bf16 hA[64 * HP];
    __shared__ __bf16 hB[64 * HP];
    __shared__ unsigned short mixs[32 * MIXP];   // half-tile staging

    const int t = threadIdx.x;
    const int lane = t & 63;
    const int wv = t >> 6;
    const int quad = lane >> 4;
    const int l15 = lane & 15;
    const int pbase = blockIdx.x * 64;

    // ---- layer 0 (8 -> 64), scalar fp32, silu, -> bf16 LDS (verbatim r3/r6)
    {
        const int i = t >> 2;                 // edge slot 0..63
        const int jg = t & 3;                 // output group of 16
        const int p = pbase + i;
        const int pc = p < E ? p : E - 1;
        const int e = perm[pc];
        const float* ar = ea + (size_t)e * 11;
        float es[8];
        #pragma unroll
        for (int k = 0; k < 8; k++) es[k] = ar[k];
        if (p < E) {
            if (jg == 0) ssort[p] = snd[e];
            if (jg == 1) evq[p] = make_float4(ar[8], ar[9], ar[10], 0.f);
        }
        union { __bf16 hb[16]; uint4 q[2]; } u;
        #pragma unroll
        for (int jj = 0; jj < 16; jj++) {
            int j = jg * 16 + jj;
            float a = 0.f;
            #pragma unroll
            for (int k = 0; k < 8; k++) a += es[k] * w0[k * 64 + j];
            u.hb[jj] = (__bf16)silu_n(a * 0.35355339f);
        }
        uint4* dst = (uint4*)&hA[i * HP + jg * 16];
        dst[0] = u.q[0]; dst[1] = u.q[1];
    }
    // No barrier: wave wv wrote rows 16wv..16wv+15 and only reads those rows
    // through layers 1-2 (compiler inserts the lgkmcnt waits).

    auto layer = [&](const __bf16* src, __bf16* dst, const __bf16* wt) {
        const int m0 = wv * 16;
        const __bf16* arow = src + (m0 + l15) * HP;
        bf16x8 A0 = *(const bf16x8*)(arow + quad * 8);         // kstep 0
        bf16x8 A1 = *(const bf16x8*)(arow + 32 + quad * 8);    // kstep 1
        #pragma unroll
        for (int c = 0; c < 4; c++) {
            bf16x8 B0 = *(const bf16x8*)(wt + ((c * 2 + 0) * 64 + lane) * 8);
            bf16x8 B1 = *(const bf16x8*)(wt + ((c * 2 + 1) * 64 + lane) * 8);
            f32x4 a = {0.f, 0.f, 0.f, 0.f};
            a = __builtin_amdgcn_mfma_f32_16x16x32_bf16(A0, B0, a, 0, 0, 0);
            a = __builtin_amdgcn_mfma_f32_16x16x32_bf16(A1, B1, a, 0, 0, 0);
            #pragma unroll
            for (int r = 0; r < 4; r++) {
                // D: col = l15, row = quad*4 + r  (scale folded into weights)
                dst[(m0 + quad * 4 + r) * HP + c * 16 + l15] = (__bf16)silu_n(a[r]);
            }
        }
    };

    layer(hA, hB, w1t);   // layer 1
    layer(hB, hA, w2t);   // layer 2

    __syncthreads();      // layer 3: each wave needs ALL rows

    // ---- layer 3 (64 -> 256): wave wv owns col chunk [64wv, 64wv+64)
    f32x4 acc[4][4];
    {
        bf16x8 B[4][2];
        #pragma unroll
        for (int c = 0; c < 4; c++)
            #pragma unroll
            for (int s = 0; s < 2; s++)
                B[c][s] = *(const bf16x8*)(w3t + ((((wv * 4 + c) * 2) + s) * 64 + lane) * 8);

        #pragma unroll
        for (int m = 0; m < 4; m++)
            #pragma unroll
            for (int c = 0; c < 4; c++)
                acc[m][c] = (f32x4){0.f, 0.f, 0.f, 0.f};

        #pragma unroll
        for (int m = 0; m < 4; m++) {
            const __bf16* arow = hA + (m * 16 + l15) * HP;
            bf16x8 A0 = *(const bf16x8*)(arow + quad * 8);
            bf16x8 A1 = *(const bf16x8*)(arow + 32 + quad * 8);
            #pragma unroll
            for (int c = 0; c < 4; c++) {
                acc[m][c] = __builtin_amdgcn_mfma_f32_16x16x32_bf16(A0, B[c][0], acc[m][c], 0, 0, 0);
                acc[m][c] = __builtin_amdgcn_mfma_f32_16x16x32_bf16(A1, B[c][1], acc[m][c], 0, 0, 0);
            }
        }
    }

    // ---- two 32-row staging passes; transposed coalesced copy-out
    #pragma unroll
    for (int half = 0; half < 2; half++) {
        __syncthreads();   // (pass 1: previous copy readers done before overwrite)
        #pragma unroll
        for (int mm = 0; mm < 2; mm++) {
            int m = half * 2 + mm;
            #pragma unroll
            for (int c = 0; c < 4; c++)
                #pragma unroll
                for (int r = 0; r < 4; r++)
                    mixs[(mm * 16 + quad * 4 + r) * MIXP + wv * 64 + c * 16 + l15] =
                        f2b(acc[m][c][r]);
        }
        __syncthreads();
        // copy out buffer rows [0,32) -> global rows [half*32, half*32+32)
        #pragma unroll
        for (int rr = 0; rr < 8; rr++) {
            int row = wv * 8 + rr;
            int grow = pbase + half * 32 + row;
            if (grow < E) {
                ushort4 v;
                v.x = mixs[row * MIXP + lane];
                v.y = mixs[row * MIXP + 64 + lane];
                v.z = mixs[row * MIXP + 128 + lane];
                v.w = mixs[row * MIXP + 192 + lane];
                *(ushort4*)(mixb + (size_t)grow * 256 + lane * 4) = v;
            }
        }
    }
}

// ---------------- kernel B: 4 waves per node, CSR walk, LDS reduce, zero atomics ----------------

__global__ __launch_bounds__(256) void gather_nodes4(
    const float* __restrict__ nf,
    const int*   __restrict__ offs,
    const int*   __restrict__ ssort,
    const float4* __restrict__ evq,
    const unsigned short* __restrict__ mixb,   // (E,64,4) transposed
    float* __restrict__ out)
{
    __shared__ float red[4][8][64];

    const int n = blockIdx.x;
    const int t = threadIdx.x;
    const int lane = t & 63;
    const int wv = t >> 6;
    const int p0 = offs[n], p1 = offs[n + 1];

    float s1 = 0.f, s2 = 0.f;
    float a10 = 0.f, a11 = 0.f, a12 = 0.f;
    float a20 = 0.f, a21 = 0.f, a22 = 0.f;

    for (int p = p0 + wv; p < p1; p += 4) {
        const int s = ssort[p];
        const float4 ev = evq[p];
        ushort4 mm = *(const ushort4*)(mixb + (size_t)p * 256 + lane * 4);
        float m0 = b2f(mm.x);
        float m1 = b2f(mm.y);
        float m2 = b2f(mm.z);
        float m3 = b2f(mm.w);
        const float* nrow = nf + (size_t)s * 256;
        float sv = nrow[lane];
        const float* vr = nrow + 64 + 3 * lane;
        float v0 = vr[0], v1 = vr[1], v2 = vr[2];

        s1 += sv * m0;
        s2 += (v0 * ev.x + v1 * ev.y + v2 * ev.z) * m1;
        a10 += v0 * m2; a11 += v1 * m2; a12 += v2 * m2;
        float tt = sv * m3;
        a20 += tt * ev.x; a21 += tt * ev.y; a22 += tt * ev.z;
    }

    red[wv][0][lane] = s1;  red[wv][1][lane] = s2;
    red[wv][2][lane] = a10; red[wv][3][lane] = a11; red[wv][4][lane] = a12;
    red[wv][5][lane] = a20; red[wv][6][lane] = a21; red[wv][7][lane] = a22;
    __syncthreads();

    if (wv == 0) {
        float r[8];
        #pragma unroll
        for (int c = 0; c < 8; c++)
            r[c] = red[0][c][lane] + red[1][c][lane] + red[2][c][lane] + red[3][c][lane];
        float* orow = out + (size_t)n * 512;
        orow[lane] = r[0];
        orow[64 + lane] = r[1] * 0.57735027f;   // INV_SQRT3 applied once
        float* o1 = orow + 128 + 3 * lane;
        o1[0] = r[2]; o1[1] = r[3]; o1[2] = r[4];
        float* o2 = orow + 320 + 3 * lane;
        o2[0] = r[5]; o2[1] = r[6]; o2[2] = r[7];
    }
}

// ---------------- fallback (atomic fused kernel) if ws too small ----------------

#define BLOCK 128
__device__ __forceinline__ void atomAddF(float* p, float v) { unsafeAtomicAdd(p, v); }

__global__ void __launch_bounds__(BLOCK) fused_mp(
    const float* __restrict__ nf, const float* __restrict__ ea,
    const int* __restrict__ snd, const int* __restrict__ rcv,
    const float* __restrict__ w0, const float* __restrict__ w1,
    const float* __restrict__ w2, const float* __restrict__ w3,
    float* __restrict__ out, int E)
{
    __shared__ float lds_h[BLOCK * 64];
    __shared__ float lds_st[BLOCK * 64];
    const int tid = threadIdx.x;
    const int lane = tid & 63;
    const int wv = tid >> 6;
    const int ebase = blockIdx.x * BLOCK;
    const int e = ebase + tid;
    const bool valid = e < E;

    float es[8];
    float ev0 = 0.f, ev1 = 0.f, ev2 = 0.f;
    int sidx = 0, ridx = 0;
    if (valid) {
        const float* p = ea + (size_t)e * 11;
        #pragma unroll
        for (int k = 0; k < 8; k++) es[k] = p[k];
        ev0 = p[8]; ev1 = p[9]; ev2 = p[10];
        sidx = snd[e]; ridx = rcv[e];
    } else {
        #pragma unroll
        for (int k = 0; k < 8; k++) es[k] = 0.f;
    }
    for (int j = 0; j < 64; j++) {
        float a = 0.f;
        #pragma unroll
        for (int k = 0; k < 8; k++) a += es[k] * w0[k * 64 + j];
        lds_h[j * BLOCK + tid] = silu_n(a * 0.35355339f);
    }
    float acc[64];
    #pragma unroll
    for (int j = 0; j < 64; j++) acc[j] = 0.f;
    for (int k = 0; k < 64; k++) {
        float hk = lds_h[k * BLOCK + tid];
        const float* wr = w1 + k * 64;
        #pragma unroll
        for (int j = 0; j < 64; j++) acc[j] += hk * wr[j];
    }
    #pragma unroll
    for (int j = 0; j < 64; j++) lds_h[j * BLOCK + tid] = silu_n(acc[j] * 0.125f);
    #pragma unroll
    for (int j = 0; j < 64; j++) acc[j] = 0.f;
    for (int k = 0; k < 64; k++) {
        float hk = lds_h[k * BLOCK + tid];
        const float* wr = w2 + k * 64;
        #pragma unroll
        for (int j = 0; j < 64; j++) acc[j] += hk * wr[j];
    }
    #pragma unroll
    for (int j = 0; j < 64; j++) lds_h[j * BLOCK + tid] = silu_n(acc[j] * 0.125f);

    const int wave_base = ebase + wv * 64;
    int wn = E - wave_base;
    const int wave_nvalid = wn < 0 ? 0 : (wn > 64 ? 64 : wn);
    float* st = lds_st + wv * 64 * 64;

    auto compute_chunk = [&](int c) {
        #pragma unroll
        for (int j = 0; j < 64; j++) acc[j] = 0.f;
        for (int k = 0; k < 64; k++) {
            float hk = lds_h[k * BLOCK + tid];
            const float* wr = w3 + k * 256 + c * 64;
            #pragma unroll
            for (int j = 0; j < 64; j++) acc[j] += hk * wr[j];
        }
        #pragma unroll
        for (int j = 0; j < 64; j++) st[j * 64 + (lane ^ j)] = acc[j] * (0.125f * 0.25f);
    };

    compute_chunk(0);
    for (int i = 0; i < wave_nvalid; i++) {
        int sI = __shfl(sidx, i);
        int rI = __shfl(ridx, i);
        float m = st[lane * 64 + (i ^ lane)];
        atomAddF(&out[(size_t)rI * 512 + lane], nf[(size_t)sI * 256 + lane] * m);
    }
    compute_chunk(1);
    for (int i = 0; i < wave_nvalid; i++) {
        int sI = __shfl(sidx, i);
        int rI = __shfl(ridx, i);
        float a0 = __shfl(ev0, i), a1 = __shfl(ev1, i), a2 = __shfl(ev2, i);
        const float* vr = nf + (size_t)sI * 256 + 64 + 3 * lane;
        float d = vr[0] * a0 + vr[1] * a1 + vr[2] * a2;
        float m = st[lane * 64 + (i ^ lane)];
        atomAddF(&out[(size_t)rI * 512 + 64 + lane], d * 0.57735027f * m);
    }
    compute_chunk(2);
    for (int i = 0; i < wave_nvalid; i++) {
        int sI = __shfl(sidx, i);
        int rI = __shfl(ridx, i);
        const float* vr = nf + (size_t)sI * 256 + 64 + 3 * lane;
        float m = st[lane * 64 + (i ^ lane)];
        float* orow = out + (size_t)rI * 512 + 128 + 3 * lane;
        atomAddF(orow + 0, vr[0] * m);
        atomAddF(orow + 1, vr[1] * m);
        atomAddF(orow + 2, vr[2] * m);
    }
    compute_chunk(3);
    for (int i = 0; i < wave_nvalid; i++) {
        int sI = __shfl(sidx, i);
        int rI = __shfl(ridx, i);
        float a0 = __shfl(ev0, i), a1 = __shfl(ev1, i), a2 = __shfl(ev2, i);
        float sv = nf[(size_t)sI * 256 + lane];
        float m = st[lane * 64 + (i ^ lane)];
        float* orow = out + (size_t)rI * 512 + 320 + 3 * lane;
        atomAddF(orow + 0, sv * a0 * m);
        atomAddF(orow + 1, sv * a1 * m);
        atomAddF(orow + 2, sv * a2 * m);
    }
}

// ---------------- launch ----------------

static inline size_t al256(size_t x) { return (x + 255) & ~(size_t)255; }

extern "C" void kernel_launch(void* const* d_in, const int* in_sizes, int n_in,
                              void* d_out, int out_size, void* d_ws, size_t ws_size,
                              hipStream_t stream)
{
    const float* nf = (const float*)d_in[0];
    const float* ea = (const float*)d_in[1];
    const int*   sn = (const int*)  d_in[2];
    const int*   rc = (const int*)  d_in[3];
    const float* w0 = (const float*)d_in[4];
    const float* w1 = (const float*)d_in[5];
    const float* w2 = (const float*)d_in[6];
    const float* w3 = (const float*)d_in[7];
    float* out = (float*)d_out;
    const int E = in_sizes[2];
    const int N = in_sizes[0] / 256;

    size_t o_cnt  = 0;
    size_t o_offs = o_cnt  + al256((size_t)(N + 1) * 4);
    size_t o_wptr = o_offs + al256((size_t)(N + 1) * 4);
    size_t o_perm = o_wptr + al256((size_t)N * 4);
    size_t o_ssrt = o_perm + al256((size_t)E * 4);
    size_t o_evq  = o_ssrt + al256((size_t)E * 4);
    size_t o_mix  = o_evq  + al256((size_t)E * 16);
    size_t o_w1t  = o_mix  + al256((size_t)E * 512);
    size_t o_w2t  = o_w1t  + al256(4096 * 2);
    size_t o_w3t  = o_w2t  + al256(4096 * 2);
    size_t need   = o_w3t  + 16384 * 2;

    if (ws_size < need) {
        hipMemsetAsync(d_out, 0, (size_t)out_size * sizeof(float), stream);
        const int blocks = (E + BLOCK - 1) / BLOCK;
        fused_mp<<<blocks, BLOCK, 0, stream>>>(nf, ea, sn, rc, w0, w1, w2, w3, out, E);
        return;
    }

    char* ws = (char*)d_ws;
    int* cnt  = (int*)(ws + o_cnt);
    int* offs = (int*)(ws + o_offs);
    int* wptr = (int*)(ws + o_wptr);
    int* perm = (int*)(ws + o_perm);
    int* ssrt = (int*)(ws + o_ssrt);
    float4* evq = (float4*)(ws + o_evq);
    unsigned short* mixb = (unsigned short*)(ws + o_mix);
    __bf16* w1t = (__bf16*)(ws + o_w1t);
    __bf16* w2t = (__bf16*)(ws + o_w2t);
    __bf16* w3t = (__bf16*)(ws + o_w3t);

    hipMemsetAsync(cnt, 0, (size_t)(N + 1) * 4, stream);
    prep_weights<<<1, 256, 0, stream>>>(w1, w2, w3, w1t, w2t, w3t);
    hist_kernel<<<(E + 255) / 256, 256, 0, stream>>>(rc, cnt, E);
    scan_kernel<<<1, 1024, 0, stream>>>(cnt, offs, wptr, N, E);
    scatter_kernel<<<(E + 255) / 256, 256, 0, stream>>>(rc, wptr, perm, E);
    mlp_mfma<<<(E + 63) / 64, 256, 0, stream>>>(
        ea, sn, perm, ssrt, evq, mixb, w0, w1t, w2t, w3t, E);
    gather_nodes4<<<N, 256, 0, stream>>>(nf, offs, ssrt, evq, mixb, out);
}